// Round 9
// baseline (149.455 us; speedup 1.0000x reference)
//
#include <hip/hip_runtime.h>

#define BB   2
#define CIN  8
#define COUT 16
#define HH   512
#define WW   1024
#define KK   9
#define NPIX (HH*WW)
#define COPY4 (1u << 20)   // uint4 elements per 16MB copy

typedef unsigned int u32;
typedef float f32x4 __attribute__((ext_vector_type(4)));
typedef float f32x2 __attribute__((ext_vector_type(2)));
typedef unsigned int u32x4 __attribute__((ext_vector_type(4)));

// fp32 -> bf16 bits, round-nearest-even
__device__ __forceinline__ u32 f2bf(float f) {
  u32 u = __float_as_uint(f);
  return (u + 0x7fffu + ((u >> 16) & 1u)) >> 16;
}
__device__ __forceinline__ float bflo(u32 u) { return __uint_as_float(u << 16); }
__device__ __forceinline__ float bfhi(u32 u) { return __uint_as_float(u & 0xffff0000u); }

// ============ 4-copy 2D-parity layout ============
// copy (pyp,pxp): 2x2-pixel blocks starting at rows 2*by+pyp, cols 2*bx+pxp.
// uint4 index = (pyp*2+pxp)<<20 + ((by*512+bx)*2 + b)*4 + dy*2 + dx
// One 64B block = 2y x 2x x 8ch bf16 of one batch.

// One thread per (by,bx,b): reads its 3x3 fp32 neighborhood for ONE batch,
// writes complete 64B blocks; thread pairs (b=t&1) make 128B-contiguous stores.
__global__ __launch_bounds__(256) void xpose3c_k(const float* __restrict__ x,
                                                 uint4* __restrict__ xt4) {
  int t = blockIdx.x * 256 + threadIdx.x;
  if (t >= (HH / 2) * (WW / 2) * BB) return;
  int b  = t & 1;
  int s  = t >> 1;
  int by = s >> 9;          // 512 block-cols
  int bx = s & 511;

  u32 pk[3][3][4];          // [r][colOff][chpair]
  #pragma unroll
  for (int j = 0; j < 4; ++j) {
    const float* c0 = x + (size_t)(b * CIN + 2 * j    ) * NPIX;
    const float* c1 = x + (size_t)(b * CIN + 2 * j + 1) * NPIX;
    int i1 = min(bx + 1, WW / 2 - 1);
    #pragma unroll
    for (int r = 0; r < 3; ++r) {
      int row = min(2 * by + r, HH - 1);
      const float2* p0 = (const float2*)(c0 + (size_t)row * WW);
      const float2* p1 = (const float2*)(c1 + (size_t)row * WW);
      float2 a0 = p0[bx], a1 = p0[i1];
      float2 b0 = p1[bx], b1 = p1[i1];
      pk[r][0][j] = f2bf(a0.x) | (f2bf(b0.x) << 16);
      pk[r][1][j] = f2bf(a0.y) | (f2bf(b0.y) << 16);
      pk[r][2][j] = f2bf(a1.x) | (f2bf(b1.x) << 16);
    }
  }

  #pragma unroll
  for (int pyp = 0; pyp < 2; ++pyp)
    #pragma unroll
    for (int pxp = 0; pxp < 2; ++pxp) {
      u32 base = ((u32)(pyp * 2 + pxp) << 20)
               + ((u32)(by * 512 + bx) * 2 + (u32)b) * 4;
      #pragma unroll
      for (int d = 0; d < 4; ++d) {
        int dy = d >> 1, dx = d & 1;
        uint4 v;
        v.x = pk[pyp + dy][pxp + dx][0];
        v.y = pk[pyp + dy][pxp + dx][1];
        v.z = pk[pyp + dy][pxp + dx][2];
        v.w = pk[pyp + dy][pxp + dx][3];
        xt4[base + d] = v;
      }
    }
}

// One sample = one asm block of 4 global_load_dwordx4 off one 64-bit vaddr.
#define LOADQ(K, B)                                                     \
  { const u32x4* _a = xbase + iq[K];                                    \
    asm volatile("global_load_dwordx4 %0, %4, off\n\t"                  \
                 "global_load_dwordx4 %1, %4, off offset:16\n\t"        \
                 "global_load_dwordx4 %2, %4, off offset:32\n\t"        \
                 "global_load_dwordx4 %3, %4, off offset:48"            \
                 : "=&v"(B##0), "=&v"(B##1), "=&v"(B##2), "=&v"(B##3)   \
                 : "v"(_a)); }

// Wait until <=N vector loads outstanding; pass-through deps pin consumers.
#define WAITQ(N, B)                                                     \
  asm volatile("s_waitcnt vmcnt(" #N ")"                                \
               : "+v"(B##0), "+v"(B##1), "+v"(B##2), "+v"(B##3))

// One thread = one (pixel,batch). Asm-pinned depth-6 gather pipeline.
__global__ __launch_bounds__(256, 3) void mconv7_k(const uint4* __restrict__ xt4,
                                                   const float* __restrict__ sm,
                                                   const float* __restrict__ weight,
                                                   const float* __restrict__ bias,
                                                   float* __restrict__ out) {
  __shared__ float sml[128 * KK * 2];
  __shared__ float wlds[KK * CIN * COUT];          // [k][c][o]

  int tid = threadIdx.x;
  {
    const f32x4* g = (const f32x4*)(sm + (size_t)blockIdx.x * 128 * KK * 2);
    f32x4* l = (f32x4*)sml;
    for (int i = tid; i < 128 * KK * 2 / 4; i += 256) l[i] = g[i];
  }
  for (int i = tid; i < KK * CIN * COUT; i += 256) {
    int k = i >> 7, c = (i >> 4) & 7, o = i & 15;
    wlds[i] = weight[(o * CIN + c) * KK + k];
  }
  __syncthreads();

  const int pl = tid & 127;
  const int b  = tid >> 7;
  const int p  = blockIdx.x * 128 + pl;

  f32x2 acc2[8];
  #pragma unroll
  for (int o2 = 0; o2 < 8; ++o2) { acc2[o2][0] = bias[2*o2]; acc2[o2][1] = bias[2*o2+1]; }
  // pin bias materialization before the asm pipeline (keep its waitcnt early)
  asm volatile("" : "+v"(acc2[0]), "+v"(acc2[1]), "+v"(acc2[2]), "+v"(acc2[3]),
                    "+v"(acc2[4]), "+v"(acc2[5]), "+v"(acc2[6]), "+v"(acc2[7]));

  const float2* smp = (const float2*)sml + pl * KK;
  const u32x4* xbase = (const u32x4*)xt4;

  // precompute all 9 block indices (registers, statically indexed)
  u32 iq[9];
  #pragma unroll
  for (int k = 0; k < KK; ++k) {
    float2 s = smp[k];
    int x0 = min(max((int)floorf(s.x), 0), WW - 2);
    int y0 = min(max((int)floorf(s.y), 0), HH - 2);
    iq[k] = ((u32)((y0 & 1) * 2 + (x0 & 1)) << 20)
          + ((u32)((y0 >> 1) * 512 + (x0 >> 1)) * 2 + (u32)b) * 4;
  }

  auto CONS = [&](int k, u32x4 v0, u32x4 v1, u32x4 v2, u32x4 v3) {
    float2 s = smp[k];
    float x0f = floorf(s.x), y0f = floorf(s.y);
    float wx = s.x - x0f, wy = s.y - y0f;
    float w00 = (1.f - wy) * (1.f - wx), w01 = (1.f - wy) * wx;
    float w10 = wy * (1.f - wx),         w11 = wy * wx;
    const float4* w4 = (const float4*)&wlds[k * (CIN * COUT)];

    float sv[8];
    #pragma unroll
    for (int j = 0; j < 4; ++j) {
      u32 a00 = v0[j], a01 = v1[j], a10 = v2[j], a11 = v3[j];
      sv[2*j]   = w00*bflo(a00) + w01*bflo(a01) + w10*bflo(a10) + w11*bflo(a11);
      sv[2*j+1] = w00*bfhi(a00) + w01*bfhi(a01) + w10*bfhi(a10) + w11*bfhi(a11);
    }
    #pragma unroll
    for (int c = 0; c < 8; ++c) {
      float s0 = sv[c];
      #pragma unroll
      for (int og = 0; og < 4; ++og) {
        float4 wv = w4[c * 4 + og];
        f32x2 wlo; wlo[0] = wv.x; wlo[1] = wv.y;
        f32x2 whi; whi[0] = wv.z; whi[1] = wv.w;
        acc2[og*2]   += wlo * s0;     // v_pk_fma_f32
        acc2[og*2+1] += whi * s0;
      }
    }
  };

  u32x4 A0,A1,A2,A3, B0,B1,B2,B3, C0,C1,C2,C3, D0,D1,D2,D3, E0,E1,E2,E3, F0,F1,F2,F3;
  LOADQ(0, A); LOADQ(1, B); LOADQ(2, C); LOADQ(3, D); LOADQ(4, E); LOADQ(5, F);
  WAITQ(20, A); CONS(0, A0,A1,A2,A3); LOADQ(6, A);
  WAITQ(20, B); CONS(1, B0,B1,B2,B3); LOADQ(7, B);
  WAITQ(20, C); CONS(2, C0,C1,C2,C3); LOADQ(8, C);
  WAITQ(20, D); CONS(3, D0,D1,D2,D3);
  WAITQ(16, E); CONS(4, E0,E1,E2,E3);
  WAITQ(12, F); CONS(5, F0,F1,F2,F3);
  WAITQ( 8, A); CONS(6, A0,A1,A2,A3);
  WAITQ( 4, B); CONS(7, B0,B1,B2,B3);
  WAITQ( 0, C); CONS(8, C0,C1,C2,C3);

  #pragma unroll
  for (int o2 = 0; o2 < 8; ++o2) {
    __builtin_nontemporal_store(acc2[o2][0], &out[(size_t)(b * COUT + 2*o2    ) * NPIX + p]);
    __builtin_nontemporal_store(acc2[o2][1], &out[(size_t)(b * COUT + 2*o2 + 1) * NPIX + p]);
  }
}

// fallback if workspace too small: gather directly from fp32 x [B][C][H][W]
__global__ __launch_bounds__(256) void mconv_direct_k(const float* __restrict__ x,
                                                      const float* __restrict__ sm,
                                                      const float* __restrict__ weight,
                                                      const float* __restrict__ bias,
                                                      float* __restrict__ out) {
  __shared__ float wlds[KK * CIN * COUT];
  int tid = threadIdx.x;
  for (int i = tid; i < KK * CIN * COUT; i += 256) {
    int k = i >> 7, c = (i >> 4) & 7, o = i & 15;
    wlds[i] = weight[(o * CIN + c) * KK + k];
  }
  __syncthreads();

  int p = blockIdx.x * 256 + tid;
  if (p >= NPIX) return;

  float acc[2][COUT];
  #pragma unroll
  for (int o = 0; o < COUT; ++o) { float bv = bias[o]; acc[0][o] = bv; acc[1][o] = bv; }

  const float2* smp = (const float2*)sm;

  for (int k = 0; k < KK; ++k) {
    float2 s = smp[(size_t)p * KK + k];
    float x0f = floorf(s.x), y0f = floorf(s.y);
    float wx = s.x - x0f, wy = s.y - y0f;
    int x0 = min(max((int)x0f, 0), WW - 1);
    int y0 = min(max((int)y0f, 0), HH - 1);
    int x1 = min(x0 + 1, WW - 1), y1 = min(y0 + 1, HH - 1);
    float w00 = (1.f - wy) * (1.f - wx), w01 = (1.f - wy) * wx;
    float w10 = wy * (1.f - wx),         w11 = wy * wx;

    float sv[2][8];
    #pragma unroll
    for (int b = 0; b < 2; ++b) {
      #pragma unroll
      for (int c = 0; c < 8; ++c) {
        const float* xp = x + (size_t)(b * CIN + c) * NPIX;
        float v00 = xp[y0 * WW + x0], v01 = xp[y0 * WW + x1];
        float v10 = xp[y1 * WW + x0], v11 = xp[y1 * WW + x1];
        sv[b][c] = w00 * v00 + w01 * v01 + w10 * v10 + w11 * v11;
      }
    }

    const float4* w4 = (const float4*)&wlds[k * (CIN * COUT)];
    #pragma unroll
    for (int c = 0; c < 8; ++c) {
      float s0 = sv[0][c], s1 = sv[1][c];
      #pragma unroll
      for (int og = 0; og < 4; ++og) {
        float4 wv = w4[c * 4 + og];
        acc[0][og*4+0] += s0 * wv.x; acc[1][og*4+0] += s1 * wv.x;
        acc[0][og*4+1] += s0 * wv.y; acc[1][og*4+1] += s1 * wv.y;
        acc[0][og*4+2] += s0 * wv.z; acc[1][og*4+2] += s1 * wv.z;
        acc[0][og*4+3] += s0 * wv.w; acc[1][og*4+3] += s1 * wv.w;
      }
    }
  }

  #pragma unroll
  for (int b = 0; b < 2; ++b)
    #pragma unroll
    for (int o = 0; o < COUT; ++o)
      out[(size_t)(b * COUT + o) * NPIX + p] = acc[b][o];
}

extern "C" void kernel_launch(void* const* d_in, const int* in_sizes, int n_in,
                              void* d_out, int out_size, void* d_ws, size_t ws_size,
                              hipStream_t stream) {
  const float* x      = (const float*)d_in[0];
  const float* sm     = (const float*)d_in[1];
  const float* weight = (const float*)d_in[2];
  const float* bias   = (const float*)d_in[3];
  float* out = (float*)d_out;

  const size_t oneCopy = (size_t)COPY4 * sizeof(uint4);   // 16 MB
  uint4* xt4 = (uint4*)d_ws;
  if (ws_size >= 4 * oneCopy) {
    hipLaunchKernelGGL(xpose3c_k, dim3((HH / 2) * (WW / 2) * BB / 256), dim3(256), 0,
                       stream, x, xt4);
    hipLaunchKernelGGL(mconv7_k, dim3(NPIX / 128), dim3(256), 0, stream,
                       xt4, sm, weight, bias, out);
  } else {
    hipLaunchKernelGGL(mconv_direct_k, dim3((NPIX + 255) / 256), dim3(256), 0, stream,
                       x, sm, weight, bias, out);
  }
}